// Round 7
// baseline (1214.334 us; speedup 1.0000x reference)
//
#include <hip/hip_runtime.h>
#include <cstdint>
#include <cstddef>

#define SEQ 32768
#define DIM 1024
#define HID 128
#define KMAXV 103   // int(0.1*1024)+1

using f4 = __attribute__((ext_vector_type(4))) float;
using f2 = __attribute__((ext_vector_type(2))) float;

// ---------------------------------------------------------------------------
// Kernel A: per-block partial column sums of x (f64, deterministic order).
// ---------------------------------------------------------------------------
__global__ __launch_bounds__(256) void pool_partial(const float* __restrict__ x,
                                                    double* __restrict__ part) {
    const int b = blockIdx.x;
    const int t = threadIdx.x;
    const int r0 = b * 128;
    double s0 = 0.0, s1 = 0.0, s2 = 0.0, s3 = 0.0;
    for (int r = 0; r < 128; ++r) {
        const float* row = x + (size_t)(r0 + r) * DIM;
        s0 += (double)row[t];
        s1 += (double)row[t + 256];
        s2 += (double)row[t + 512];
        s3 += (double)row[t + 768];
    }
    double* p = part + (size_t)b * DIM;
    p[t] = s0; p[t + 256] = s1; p[t + 512] = s2; p[t + 768] = s3;
}

// ---------------------------------------------------------------------------
// Kernel B: finish pooling, complexity net (exact erf GELU, sigmoid), k.
// ---------------------------------------------------------------------------
__global__ __launch_bounds__(1024) void tiny_net(const double* __restrict__ part,
                                                 const float* __restrict__ w1,
                                                 const float* __restrict__ b1,
                                                 const float* __restrict__ w2,
                                                 const float* __restrict__ b2,
                                                 float* __restrict__ out_scalars,
                                                 int* __restrict__ kout) {
    __shared__ double pooled[DIM];
    __shared__ double hidv[HID];
    const int t = threadIdx.x;

    double s = 0.0;
    for (int b = 0; b < 256; ++b) s += part[(size_t)b * DIM + t];
    pooled[t] = s / (double)SEQ;
    __syncthreads();

    if (t < HID) {
        double h = (double)b1[t];
        for (int d = 0; d < DIM; ++d) h += pooled[d] * (double)w1[d * HID + t];
        h = 0.5 * h * (1.0 + erf(h * 0.70710678118654752440));
        hidv[t] = h;
    }
    __syncthreads();

    if (t == 0) {
        double z = (double)b2[0];
        for (int j = 0; j < HID; ++j) z += hidv[j] * (double)w2[j];
        double c = 1.0 / (1.0 + exp(-z));
        double ar = 0.01 + 0.09 * c;
        int k = (int)(ar * (double)DIM);  // trunc
        if (k < 1) k = 1;
        if (k > KMAXV) k = KMAXV;
        out_scalars[0] = (float)c;
        out_scalars[1] = (float)ar;
        out_scalars[2] = (float)k;
        *kout = k;
    }
}

// ---------------------------------------------------------------------------
// Panel kernels: importance GEMM with numpy/OpenBLAS f32 semantics — NUMERICS
// FROZEN: per element, sequential-k fma within panels {384,320,320}, panel
// sums added in order ((P1+P2)+P3). v_pk_fma_f32 is IEEE fma per 32-bit lane,
// so per-element op order/rounding is bit-identical to rounds 2/3/6.
//
// Structure: 512 threads; thread owns 16 rows x 2 contiguous cols (c2=2t) ->
// zero wq duplication (halves L2 read traffic vs R6's rg-duplicated loads).
// Live set in FMA loop: pacc f2[16] (32) + wq cur/next f2 x4 (16) + xv (4)
// + addr ~ 60 regs -> fits the ~64-VGPR budget with room for the EXPLICIT
// NEXT-STEP wq PRELOAD (software rotation), which hides the ~200cyc L2
// latency under the ~300cyc packed-FMA block per step (R6: 46% idle).
// MODE 0: out = pacc          (P1)
// MODE 1: out = out + pacc    (fl(P1+P2))
// MODE 2: dot = out + pacc, epilogue, per-row dynamic-k selection (u32 radix
//         search, tie-inclusive >=), masked x written over out in-place.
// ---------------------------------------------------------------------------
#define BM 16
#define CBLOCK 512

template<int K0, int K1, int MODE>
__global__ __launch_bounds__(CBLOCK) void panel_kernel(const float* __restrict__ x,
                                                       const float* __restrict__ wg,
                                                       const float* __restrict__ bg,
                                                       const float* __restrict__ rm,
                                                       const float* __restrict__ rv,
                                                       const int* __restrict__ kptr,
                                                       float* __restrict__ out) {
    constexpr int PK = K1 - K0;
    constexpr int PK4 = PK / 4;
    constexpr int LDSF = (MODE == 2 && 8 * DIM > BM * PK) ? 8 * DIM : BM * PK;
    __shared__ float lbuf[LDSF];

    const int t = threadIdx.x;
    const int c2 = t << 1;           // 2 contiguous columns c2, c2+1
    const int row0 = blockIdx.x * BM;

    // stage x slice [row0:row0+16][K0:K1] (coalesced float4)
    {
        f4* xl = (f4*)lbuf;
        for (int i = t; i < BM * PK4; i += CBLOCK) {
            const int r = i / PK4, cc = i - r * PK4;
            xl[i] = *(const f4*)(x + (size_t)(row0 + r) * DIM + K0 + 4 * cc);
        }
    }
    __syncthreads();

    f2 pacc[16];
#pragma unroll
    for (int m = 0; m < 16; ++m) { pacc[m][0] = 0.0f; pacc[m][1] = 0.0f; }

    const float* xrow = lbuf;
    const float* wbase = wg + c2;

    // software-rotated wq: preload step K0, inside the loop load step kk0+4
    // BEFORE consuming the current step's values.
    f2 wc0 = *(const f2*)(wbase + (size_t)(K0 + 0) * DIM);
    f2 wc1 = *(const f2*)(wbase + (size_t)(K0 + 1) * DIM);
    f2 wc2 = *(const f2*)(wbase + (size_t)(K0 + 2) * DIM);
    f2 wc3 = *(const f2*)(wbase + (size_t)(K0 + 3) * DIM);

    for (int kk0 = K0; kk0 < K1; kk0 += 4) {
        const int kn = (kk0 + 4 < K1) ? (kk0 + 4) : K0;   // last iter: dummy reload
        const f2 wn0 = *(const f2*)(wbase + (size_t)(kn + 0) * DIM);
        const f2 wn1 = *(const f2*)(wbase + (size_t)(kn + 1) * DIM);
        const f2 wn2 = *(const f2*)(wbase + (size_t)(kn + 2) * DIM);
        const f2 wn3 = *(const f2*)(wbase + (size_t)(kn + 3) * DIM);

#pragma unroll
        for (int m = 0; m < 16; ++m) {
            const f4 xv = *(const f4*)(xrow + m * PK + (kk0 - K0));  // LDS broadcast
            f2 xb;
            xb[0] = xv[0]; xb[1] = xv[0];
            pacc[m] = __builtin_elementwise_fma(xb, wc0, pacc[m]);   // k = kk0
            xb[0] = xv[1]; xb[1] = xv[1];
            pacc[m] = __builtin_elementwise_fma(xb, wc1, pacc[m]);   // k = kk0+1
            xb[0] = xv[2]; xb[1] = xv[2];
            pacc[m] = __builtin_elementwise_fma(xb, wc2, pacc[m]);   // k = kk0+2
            xb[0] = xv[3]; xb[1] = xv[3];
            pacc[m] = __builtin_elementwise_fma(xb, wc3, pacc[m]);   // k = kk0+3
        }
        wc0 = wn0; wc1 = wn1; wc2 = wn2; wc3 = wn3;
    }

    if constexpr (MODE == 0) {
#pragma unroll
        for (int m = 0; m < 16; ++m)
            *(f2*)(out + (size_t)(row0 + m) * DIM + c2) = pacc[m];
        return;
    } else if constexpr (MODE == 1) {
#pragma unroll
        for (int m = 0; m < 16; ++m) {
            float* op = out + (size_t)(row0 + m) * DIM + c2;
            f2 d = *(const f2*)op;
            d[0] = d[0] + pacc[m][0];       // fl(P1+P2), plain f32 adds
            d[1] = d[1] + pacc[m][1];
            *(f2*)op = d;
        }
        return;
    } else {
        // MODE 2: finalize dot, epilogue, selection, masked write
        f2 dot[16];
#pragma unroll
        for (int m = 0; m < 16; ++m) {
            const f2 d = *(const f2*)(out + (size_t)(row0 + m) * DIM + c2);
            dot[m][0] = d[0] + pacc[m][0];  // fl((P1+P2)+P3)
            dot[m][1] = d[1] + pacc[m][1];
        }

        // f32 epilogue, op-for-op as numpy
        const f2 vbg = *(const f2*)(bg + c2);
        const f2 vrm = *(const f2*)(rm + c2);
        const f2 vrv = *(const f2*)(rv + c2);
        f2 vden;
        vden[0] = sqrtf(vrv[0]) + 1e-6f;
        vden[1] = sqrtf(vrv[1]) + 1e-6f;

        f2 imp[16];
#pragma unroll
        for (int m = 0; m < 16; ++m) {
            imp[m][0] = (fabsf(dot[m][0] + vbg[0]) - vrm[0]) / vden[0];
            imp[m][1] = (fabsf(dot[m][1] + vbg[1]) - vrm[1]) / vden[1];
        }

        int kval = *kptr;
        if (kval < 1) kval = 1;
        if (kval > DIM) kval = DIM;

        float (*selbuf)[DIM] = (float (*)[DIM])lbuf;

        // two chunks of 8 rows; one wave per row does exact kth-largest selection
        for (int ch = 0; ch < 2; ++ch) {
            __syncthreads();
#pragma unroll
            for (int m = 0; m < 8; ++m)
                *(f2*)(&selbuf[m][c2]) = imp[ch * 8 + m];
            __syncthreads();

            const int w = t >> 6;    // wave id 0..7 -> row within chunk
            const int l = t & 63;    // lane
            const size_t srow = (size_t)(row0 + ch * 8 + w);

            // monotonic u32 keys for descending f32 order
            unsigned keys[16];
#pragma unroll
            for (int j = 0; j < 4; ++j) {
                const f4 v = *(const f4*)(&selbuf[w][4 * l + 256 * j]);
#pragma unroll
                for (int i = 0; i < 4; ++i) {
                    const unsigned u = __float_as_uint(v[i]);
                    keys[j * 4 + i] = (u & 0x80000000u) ? ~u : (u | 0x80000000u);
                }
            }

            // bitwise search for the kth-largest key: largest T with count(>=T) >= k
            unsigned pref = 0u;
            for (int b = 31; b >= 0; --b) {
                const unsigned tt = pref | (1u << b);
                int cnt = 0;
#pragma unroll
                for (int j = 0; j < 16; ++j) cnt += (keys[j] >= tt) ? 1 : 0;
#pragma unroll
                for (int off = 32; off >= 1; off >>= 1) cnt += __shfl_xor(cnt, off, 64);
                if (cnt >= kval) pref = tt;
            }

            // mask = importance >= kth (tie-inclusive); coalesced float4 out
            const float* xr = x + srow * DIM;
            float* orow = out + srow * DIM;
#pragma unroll
            for (int j = 0; j < 4; ++j) {
                const f4 xv = *(const f4*)(xr + 4 * l + 256 * j);
                f4 o;
#pragma unroll
                for (int i = 0; i < 4; ++i) o[i] = (keys[j * 4 + i] >= pref) ? xv[i] : 0.0f;
                *(f4*)(orow + 4 * l + 256 * j) = o;
            }
        }
    }
}

// ---------------------------------------------------------------------------
extern "C" void kernel_launch(void* const* d_in, const int* in_sizes, int n_in,
                              void* d_out, int out_size, void* d_ws, size_t ws_size,
                              hipStream_t stream) {
    const float* x  = (const float*)d_in[0];
    const float* w1 = (const float*)d_in[1];
    const float* b1 = (const float*)d_in[2];
    const float* w2 = (const float*)d_in[3];
    const float* b2 = (const float*)d_in[4];
    const float* wg = (const float*)d_in[5];
    const float* bg = (const float*)d_in[6];
    const float* rm = (const float*)d_in[7];
    const float* rv = (const float*)d_in[8];
    float* out = (float*)d_out;

    double* part = (double*)d_ws;                                  // 256*1024 f64 = 2 MB
    int* kptr = (int*)((char*)d_ws + (size_t)256 * DIM * sizeof(double));

    pool_partial<<<256, 256, 0, stream>>>(x, part);
    tiny_net<<<1, 1024, 0, stream>>>(part, w1, b1, w2, b2,
                                     out + (size_t)SEQ * DIM, kptr);
    panel_kernel<0,   384,  0><<<SEQ / BM, CBLOCK, 0, stream>>>(x, wg, bg, rm, rv, kptr, out);
    panel_kernel<384, 704,  1><<<SEQ / BM, CBLOCK, 0, stream>>>(x, wg, bg, rm, rv, kptr, out);
    panel_kernel<704, 1024, 2><<<SEQ / BM, CBLOCK, 0, stream>>>(x, wg, bg, rm, rv, kptr, out);
}

// Round 8
// 1058.667 us; speedup vs baseline: 1.1470x; 1.1470x over previous
//
#include <hip/hip_runtime.h>
#include <cstdint>
#include <cstddef>

#define SEQ 32768
#define DIM 1024
#define HID 128
#define KMAXV 103   // int(0.1*1024)+1

using f4 = __attribute__((ext_vector_type(4))) float;
using f2 = __attribute__((ext_vector_type(2))) float;

// ---------------------------------------------------------------------------
// Kernel A: per-block partial column sums of x (f64, deterministic order).
// ---------------------------------------------------------------------------
__global__ __launch_bounds__(256) void pool_partial(const float* __restrict__ x,
                                                    double* __restrict__ part) {
    const int b = blockIdx.x;
    const int t = threadIdx.x;
    const int r0 = b * 128;
    double s0 = 0.0, s1 = 0.0, s2 = 0.0, s3 = 0.0;
    for (int r = 0; r < 128; ++r) {
        const float* row = x + (size_t)(r0 + r) * DIM;
        s0 += (double)row[t];
        s1 += (double)row[t + 256];
        s2 += (double)row[t + 512];
        s3 += (double)row[t + 768];
    }
    double* p = part + (size_t)b * DIM;
    p[t] = s0; p[t + 256] = s1; p[t + 512] = s2; p[t + 768] = s3;
}

// ---------------------------------------------------------------------------
// Kernel B: finish pooling, complexity net (exact erf GELU, sigmoid), k.
// ---------------------------------------------------------------------------
__global__ __launch_bounds__(1024) void tiny_net(const double* __restrict__ part,
                                                 const float* __restrict__ w1,
                                                 const float* __restrict__ b1,
                                                 const float* __restrict__ w2,
                                                 const float* __restrict__ b2,
                                                 float* __restrict__ out_scalars,
                                                 int* __restrict__ kout) {
    __shared__ double pooled[DIM];
    __shared__ double hidv[HID];
    const int t = threadIdx.x;

    double s = 0.0;
    for (int b = 0; b < 256; ++b) s += part[(size_t)b * DIM + t];
    pooled[t] = s / (double)SEQ;
    __syncthreads();

    if (t < HID) {
        double h = (double)b1[t];
        for (int d = 0; d < DIM; ++d) h += pooled[d] * (double)w1[d * HID + t];
        h = 0.5 * h * (1.0 + erf(h * 0.70710678118654752440));
        hidv[t] = h;
    }
    __syncthreads();

    if (t == 0) {
        double z = (double)b2[0];
        for (int j = 0; j < HID; ++j) z += hidv[j] * (double)w2[j];
        double c = 1.0 / (1.0 + exp(-z));
        double ar = 0.01 + 0.09 * c;
        int k = (int)(ar * (double)DIM);  // trunc
        if (k < 1) k = 1;
        if (k > KMAXV) k = KMAXV;
        out_scalars[0] = (float)c;
        out_scalars[1] = (float)ar;
        out_scalars[2] = (float)k;
        *kout = k;
    }
}

// ---------------------------------------------------------------------------
// Panel kernels: importance GEMM with numpy/OpenBLAS f32 semantics — NUMERICS
// FROZEN: per element, sequential-k fmaf within panels {384,320,320}, panel
// sums added in order ((P1+P2)+P3). Bit-identical per-element op order to the
// round-2/3/6 passing kernels.
//
// R7 diagnosis: the kernel was LDS-pipe-bound (16 ds_read_b128 broadcasts of
// block-uniform x per wave-step ~ 1536 LDS-cyc/block-step -> 492 us predicted,
// 460 measured). Fix: x values are BLOCK-UNIFORM -> read them directly from
// global at uniform addresses so LLVM selects s_load into SGPRs (x is const
// __restrict__, address = arg + blockIdx + loop var, all uniform). v_fma_f32
// takes one SGPR operand -> zero LDS traffic, zero x VGPRs, SMEM rides the
// idle scalar pipe. No x staging; modes 0/1 use no LDS at all (occupancy to
// the 32-wave/CU cap). wq stays VGPR with software rotation.
// MODE 0: out = pacc          (P1)
// MODE 1: out = out + pacc    (fl(P1+P2))
// MODE 2: dot = out + pacc, epilogue, per-row dynamic-k selection (u32 radix
//         search, tie-inclusive >=), masked x written over out in-place.
// ---------------------------------------------------------------------------
#define BM 16
#define CBLOCK 512

template<int K0, int K1, int MODE>
__global__ __launch_bounds__(CBLOCK) void panel_kernel(const float* __restrict__ x,
                                                       const float* __restrict__ wg,
                                                       const float* __restrict__ bg,
                                                       const float* __restrict__ rm,
                                                       const float* __restrict__ rv,
                                                       const int* __restrict__ kptr,
                                                       float* __restrict__ out) {
    __shared__ float lbuf[(MODE == 2) ? 8 * DIM : 1];

    const int t = threadIdx.x;
    const int c2 = t << 1;           // 2 contiguous columns c2, c2+1
    const int row0 = blockIdx.x * BM;

    float pacc[16][2];
#pragma unroll
    for (int m = 0; m < 16; ++m) { pacc[m][0] = 0.0f; pacc[m][1] = 0.0f; }

    const float* wbase = wg + c2;

    // software-rotated wq: preload step K0, inside the loop load step kk0+4
    // BEFORE consuming the current step's values.
    f2 wc0 = *(const f2*)(wbase + (size_t)(K0 + 0) * DIM);
    f2 wc1 = *(const f2*)(wbase + (size_t)(K0 + 1) * DIM);
    f2 wc2 = *(const f2*)(wbase + (size_t)(K0 + 2) * DIM);
    f2 wc3 = *(const f2*)(wbase + (size_t)(K0 + 3) * DIM);

    for (int kk0 = K0; kk0 < K1; kk0 += 4) {
        const int kn = (kk0 + 4 < K1) ? (kk0 + 4) : K0;   // last iter: dummy reload
        const f2 wn0 = *(const f2*)(wbase + (size_t)(kn + 0) * DIM);
        const f2 wn1 = *(const f2*)(wbase + (size_t)(kn + 1) * DIM);
        const f2 wn2 = *(const f2*)(wbase + (size_t)(kn + 2) * DIM);
        const f2 wn3 = *(const f2*)(wbase + (size_t)(kn + 3) * DIM);

        // block-uniform x reads -> SGPR via s_load (scalar pipe, no LDS)
        const float* xp = x + (size_t)row0 * DIM + kk0;
#pragma unroll
        for (int m = 0; m < 16; ++m) {
            const f4 xq = *(const f4*)(xp + m * DIM);   // uniform s_load_dwordx4
            float a0 = pacc[m][0], a1 = pacc[m][1];
            a0 = fmaf(xq[0], wc0[0], a0); a1 = fmaf(xq[0], wc0[1], a1);  // k=kk0
            a0 = fmaf(xq[1], wc1[0], a0); a1 = fmaf(xq[1], wc1[1], a1);  // k=kk0+1
            a0 = fmaf(xq[2], wc2[0], a0); a1 = fmaf(xq[2], wc2[1], a1);  // k=kk0+2
            a0 = fmaf(xq[3], wc3[0], a0); a1 = fmaf(xq[3], wc3[1], a1);  // k=kk0+3
            pacc[m][0] = a0; pacc[m][1] = a1;
        }
        wc0 = wn0; wc1 = wn1; wc2 = wn2; wc3 = wn3;
    }

    if constexpr (MODE == 0) {
#pragma unroll
        for (int m = 0; m < 16; ++m) {
            f2 v; v[0] = pacc[m][0]; v[1] = pacc[m][1];
            *(f2*)(out + (size_t)(row0 + m) * DIM + c2) = v;
        }
        return;
    } else if constexpr (MODE == 1) {
#pragma unroll
        for (int m = 0; m < 16; ++m) {
            float* op = out + (size_t)(row0 + m) * DIM + c2;
            f2 d = *(const f2*)op;
            d[0] = d[0] + pacc[m][0];       // fl(P1+P2), plain f32 adds
            d[1] = d[1] + pacc[m][1];
            *(f2*)op = d;
        }
        return;
    } else {
        // MODE 2: finalize dot, epilogue, selection, masked write
        float dot[16][2];
#pragma unroll
        for (int m = 0; m < 16; ++m) {
            const f2 d = *(const f2*)(out + (size_t)(row0 + m) * DIM + c2);
            dot[m][0] = d[0] + pacc[m][0];  // fl((P1+P2)+P3)
            dot[m][1] = d[1] + pacc[m][1];
        }

        // f32 epilogue, op-for-op as numpy
        const f2 vbg = *(const f2*)(bg + c2);
        const f2 vrm = *(const f2*)(rm + c2);
        const f2 vrv = *(const f2*)(rv + c2);
        f2 vden;
        vden[0] = sqrtf(vrv[0]) + 1e-6f;
        vden[1] = sqrtf(vrv[1]) + 1e-6f;

        f2 imp[16];
#pragma unroll
        for (int m = 0; m < 16; ++m) {
            imp[m][0] = (fabsf(dot[m][0] + vbg[0]) - vrm[0]) / vden[0];
            imp[m][1] = (fabsf(dot[m][1] + vbg[1]) - vrm[1]) / vden[1];
        }

        int kval = *kptr;
        if (kval < 1) kval = 1;
        if (kval > DIM) kval = DIM;

        float (*selbuf)[DIM] = (float (*)[DIM])lbuf;

        // two chunks of 8 rows; one wave per row does exact kth-largest selection
        for (int ch = 0; ch < 2; ++ch) {
            __syncthreads();
#pragma unroll
            for (int m = 0; m < 8; ++m)
                *(f2*)(&selbuf[m][c2]) = imp[ch * 8 + m];
            __syncthreads();

            const int w = t >> 6;    // wave id 0..7 -> row within chunk
            const int l = t & 63;    // lane
            const size_t srow = (size_t)(row0 + ch * 8 + w);

            // monotonic u32 keys for descending f32 order
            unsigned keys[16];
#pragma unroll
            for (int j = 0; j < 4; ++j) {
                const f4 v = *(const f4*)(&selbuf[w][4 * l + 256 * j]);
#pragma unroll
                for (int i = 0; i < 4; ++i) {
                    const unsigned u = __float_as_uint(v[i]);
                    keys[j * 4 + i] = (u & 0x80000000u) ? ~u : (u | 0x80000000u);
                }
            }

            // bitwise search for the kth-largest key: largest T with count(>=T) >= k
            unsigned pref = 0u;
            for (int b = 31; b >= 0; --b) {
                const unsigned tt = pref | (1u << b);
                int cnt = 0;
#pragma unroll
                for (int j = 0; j < 16; ++j) cnt += (keys[j] >= tt) ? 1 : 0;
#pragma unroll
                for (int off = 32; off >= 1; off >>= 1) cnt += __shfl_xor(cnt, off, 64);
                if (cnt >= kval) pref = tt;
            }

            // mask = importance >= kth (tie-inclusive); coalesced float4 out
            const float* xr = x + srow * DIM;
            float* orow = out + srow * DIM;
#pragma unroll
            for (int j = 0; j < 4; ++j) {
                const f4 xv = *(const f4*)(xr + 4 * l + 256 * j);
                f4 o;
#pragma unroll
                for (int i = 0; i < 4; ++i) o[i] = (keys[j * 4 + i] >= pref) ? xv[i] : 0.0f;
                *(f4*)(orow + 4 * l + 256 * j) = o;
            }
        }
    }
}

// ---------------------------------------------------------------------------
extern "C" void kernel_launch(void* const* d_in, const int* in_sizes, int n_in,
                              void* d_out, int out_size, void* d_ws, size_t ws_size,
                              hipStream_t stream) {
    const float* x  = (const float*)d_in[0];
    const float* w1 = (const float*)d_in[1];
    const float* b1 = (const float*)d_in[2];
    const float* w2 = (const float*)d_in[3];
    const float* b2 = (const float*)d_in[4];
    const float* wg = (const float*)d_in[5];
    const float* bg = (const float*)d_in[6];
    const float* rm = (const float*)d_in[7];
    const float* rv = (const float*)d_in[8];
    float* out = (float*)d_out;

    double* part = (double*)d_ws;                                  // 256*1024 f64 = 2 MB
    int* kptr = (int*)((char*)d_ws + (size_t)256 * DIM * sizeof(double));

    pool_partial<<<256, 256, 0, stream>>>(x, part);
    tiny_net<<<1, 1024, 0, stream>>>(part, w1, b1, w2, b2,
                                     out + (size_t)SEQ * DIM, kptr);
    panel_kernel<0,   384,  0><<<SEQ / BM, CBLOCK, 0, stream>>>(x, wg, bg, rm, rv, kptr, out);
    panel_kernel<384, 704,  1><<<SEQ / BM, CBLOCK, 0, stream>>>(x, wg, bg, rm, rv, kptr, out);
    panel_kernel<704, 1024, 2><<<SEQ / BM, CBLOCK, 0, stream>>>(x, wg, bg, rm, rv, kptr, out);
}

// Round 9
// 1045.064 us; speedup vs baseline: 1.1620x; 1.0130x over previous
//
#include <hip/hip_runtime.h>
#include <cstdint>
#include <cstddef>

#define SEQ 32768
#define DIM 1024
#define HID 128
#define KMAXV 103   // int(0.1*1024)+1

using f4 = __attribute__((ext_vector_type(4))) float;
using f2 = __attribute__((ext_vector_type(2))) float;

// ---------------------------------------------------------------------------
// Kernel A: per-block partial column sums of x (f64, deterministic order).
// ---------------------------------------------------------------------------
__global__ __launch_bounds__(256) void pool_partial(const float* __restrict__ x,
                                                    double* __restrict__ part) {
    const int b = blockIdx.x;
    const int t = threadIdx.x;
    const int r0 = b * 128;
    double s0 = 0.0, s1 = 0.0, s2 = 0.0, s3 = 0.0;
    for (int r = 0; r < 128; ++r) {
        const float* row = x + (size_t)(r0 + r) * DIM;
        s0 += (double)row[t];
        s1 += (double)row[t + 256];
        s2 += (double)row[t + 512];
        s3 += (double)row[t + 768];
    }
    double* p = part + (size_t)b * DIM;
    p[t] = s0; p[t + 256] = s1; p[t + 512] = s2; p[t + 768] = s3;
}

// ---------------------------------------------------------------------------
// Kernel B: finish pooling, complexity net (exact erf GELU, sigmoid), k.
// ---------------------------------------------------------------------------
__global__ __launch_bounds__(1024) void tiny_net(const double* __restrict__ part,
                                                 const float* __restrict__ w1,
                                                 const float* __restrict__ b1,
                                                 const float* __restrict__ w2,
                                                 const float* __restrict__ b2,
                                                 float* __restrict__ out_scalars,
                                                 int* __restrict__ kout) {
    __shared__ double pooled[DIM];
    __shared__ double hidv[HID];
    const int t = threadIdx.x;

    double s = 0.0;
    for (int b = 0; b < 256; ++b) s += part[(size_t)b * DIM + t];
    pooled[t] = s / (double)SEQ;
    __syncthreads();

    if (t < HID) {
        double h = (double)b1[t];
        for (int d = 0; d < DIM; ++d) h += pooled[d] * (double)w1[d * HID + t];
        h = 0.5 * h * (1.0 + erf(h * 0.70710678118654752440));
        hidv[t] = h;
    }
    __syncthreads();

    if (t == 0) {
        double z = (double)b2[0];
        for (int j = 0; j < HID; ++j) z += hidv[j] * (double)w2[j];
        double c = 1.0 / (1.0 + exp(-z));
        double ar = 0.01 + 0.09 * c;
        int k = (int)(ar * (double)DIM);  // trunc
        if (k < 1) k = 1;
        if (k > KMAXV) k = KMAXV;
        out_scalars[0] = (float)c;
        out_scalars[1] = (float)ar;
        out_scalars[2] = (float)k;
        *kout = k;
    }
}

// ---------------------------------------------------------------------------
// GEMM with numpy/OpenBLAS f32 semantics — NUMERICS FROZEN: per element,
// sequential-k fmaf within panels {384,320,320}, panel sums added in order
// ((P1+P2)+P3). Bit-identical per-element op order to rounds 2/3/6/8.
//
// x values are block-uniform -> read at uniform addresses so LLVM selects
// s_load into SGPRs (scalar pipe, no LDS, no x VGPRs); v_fma_f32 takes the
// SGPR operand directly. wq is per-thread (2 contiguous cols, c2=2t) with
// DEPTH-2 software rotation so each global load has ~512 cyc of FMA cover.
//
// panel1_kernel:  out = P1                                (K 0..384)
// panel23_kernel: paccA = P2 (384..704); d12 = fl(out+paccA);
//                 paccB = P3 (704..1024); dot = fl(d12+paccB);
//                 epilogue + per-row dynamic-k selection (u32 radix search,
//                 tie-inclusive >=), masked x written over out in-place.
// ---------------------------------------------------------------------------
#define BM 16
#define CBLOCK 512

// one K-panel accumulation: pacc[m][2] over [K0,K1), depth-2 wq rotation
template<int K0, int K1>
__device__ __forceinline__ void panel_acc(const float* __restrict__ x,
                                          const float* __restrict__ wbase,
                                          int row0, float pacc[16][2]) {
#pragma unroll
    for (int m = 0; m < 16; ++m) { pacc[m][0] = 0.0f; pacc[m][1] = 0.0f; }

    // depth-2 rotation: wc = step kk0, wn = step kk0+4, load wn2 = kk0+8
    f2 wc0 = *(const f2*)(wbase + (size_t)(K0 + 0) * DIM);
    f2 wc1 = *(const f2*)(wbase + (size_t)(K0 + 1) * DIM);
    f2 wc2 = *(const f2*)(wbase + (size_t)(K0 + 2) * DIM);
    f2 wc3 = *(const f2*)(wbase + (size_t)(K0 + 3) * DIM);
    f2 wn0 = *(const f2*)(wbase + (size_t)(K0 + 4) * DIM);
    f2 wn1 = *(const f2*)(wbase + (size_t)(K0 + 5) * DIM);
    f2 wn2_ = *(const f2*)(wbase + (size_t)(K0 + 6) * DIM);
    f2 wn3 = *(const f2*)(wbase + (size_t)(K0 + 7) * DIM);

    for (int kk0 = K0; kk0 < K1; kk0 += 4) {
        const int kp = kk0 + 8;
        const int kn2 = (kp < K1) ? kp : K0;              // tail: dummy reload
        const f2 p0 = *(const f2*)(wbase + (size_t)(kn2 + 0) * DIM);
        const f2 p1 = *(const f2*)(wbase + (size_t)(kn2 + 1) * DIM);
        const f2 p2 = *(const f2*)(wbase + (size_t)(kn2 + 2) * DIM);
        const f2 p3 = *(const f2*)(wbase + (size_t)(kn2 + 3) * DIM);

        // block-uniform x reads -> SGPR via s_load (scalar pipe)
        const float* xp = x + (size_t)row0 * DIM + kk0;
#pragma unroll
        for (int m = 0; m < 16; ++m) {
            const f4 xq = *(const f4*)(xp + m * DIM);     // s_load_dwordx4
            float a0 = pacc[m][0], a1 = pacc[m][1];
            a0 = fmaf(xq[0], wc0[0], a0); a1 = fmaf(xq[0], wc0[1], a1);  // k=kk0
            a0 = fmaf(xq[1], wc1[0], a0); a1 = fmaf(xq[1], wc1[1], a1);  // k=kk0+1
            a0 = fmaf(xq[2], wc2[0], a0); a1 = fmaf(xq[2], wc2[1], a1);  // k=kk0+2
            a0 = fmaf(xq[3], wc3[0], a0); a1 = fmaf(xq[3], wc3[1], a1);  // k=kk0+3
            pacc[m][0] = a0; pacc[m][1] = a1;
        }
        wc0 = wn0; wc1 = wn1; wc2 = wn2_; wc3 = wn3;
        wn0 = p0;  wn1 = p1;  wn2_ = p2;  wn3 = p3;
    }
}

__global__ __launch_bounds__(CBLOCK) void panel1_kernel(const float* __restrict__ x,
                                                        const float* __restrict__ wg,
                                                        float* __restrict__ out) {
    const int t = threadIdx.x;
    const int c2 = t << 1;
    const int row0 = blockIdx.x * BM;

    float pacc[16][2];
    panel_acc<0, 384>(x, wg + c2, row0, pacc);

#pragma unroll
    for (int m = 0; m < 16; ++m) {
        f2 v; v[0] = pacc[m][0]; v[1] = pacc[m][1];
        *(f2*)(out + (size_t)(row0 + m) * DIM + c2) = v;
    }
}

__global__ __launch_bounds__(CBLOCK) void panel23_kernel(const float* __restrict__ x,
                                                         const float* __restrict__ wg,
                                                         const float* __restrict__ bg,
                                                         const float* __restrict__ rm,
                                                         const float* __restrict__ rv,
                                                         const int* __restrict__ kptr,
                                                         float* __restrict__ out) {
    __shared__ float lbuf[8 * DIM];

    const int t = threadIdx.x;
    const int c2 = t << 1;
    const int row0 = blockIdx.x * BM;

    float pacc[16][2];

    // P2 panel, then d12 = fl(P1 + P2) (exact same add as R8 MODE 1)
    panel_acc<384, 704>(x, wg + c2, row0, pacc);
    float d12[16][2];
#pragma unroll
    for (int m = 0; m < 16; ++m) {
        const f2 d = *(const f2*)(out + (size_t)(row0 + m) * DIM + c2);
        d12[m][0] = d[0] + pacc[m][0];
        d12[m][1] = d[1] + pacc[m][1];
    }

    // P3 panel, then dot = fl((P1+P2) + P3)
    panel_acc<704, 1024>(x, wg + c2, row0, pacc);
    float dot[16][2];
#pragma unroll
    for (int m = 0; m < 16; ++m) {
        dot[m][0] = d12[m][0] + pacc[m][0];
        dot[m][1] = d12[m][1] + pacc[m][1];
    }

    // f32 epilogue, op-for-op as numpy
    const f2 vbg = *(const f2*)(bg + c2);
    const f2 vrm = *(const f2*)(rm + c2);
    const f2 vrv = *(const f2*)(rv + c2);
    f2 vden;
    vden[0] = sqrtf(vrv[0]) + 1e-6f;
    vden[1] = sqrtf(vrv[1]) + 1e-6f;

    f2 imp[16];
#pragma unroll
    for (int m = 0; m < 16; ++m) {
        imp[m][0] = (fabsf(dot[m][0] + vbg[0]) - vrm[0]) / vden[0];
        imp[m][1] = (fabsf(dot[m][1] + vbg[1]) - vrm[1]) / vden[1];
    }

    int kval = *kptr;
    if (kval < 1) kval = 1;
    if (kval > DIM) kval = DIM;

    float (*selbuf)[DIM] = (float (*)[DIM])lbuf;

    // two chunks of 8 rows; one wave per row does exact kth-largest selection
    for (int ch = 0; ch < 2; ++ch) {
        __syncthreads();
#pragma unroll
        for (int m = 0; m < 8; ++m)
            *(f2*)(&selbuf[m][c2]) = imp[ch * 8 + m];
        __syncthreads();

        const int w = t >> 6;    // wave id 0..7 -> row within chunk
        const int l = t & 63;    // lane
        const size_t srow = (size_t)(row0 + ch * 8 + w);

        // monotonic u32 keys for descending f32 order
        unsigned keys[16];
#pragma unroll
        for (int j = 0; j < 4; ++j) {
            const f4 v = *(const f4*)(&selbuf[w][4 * l + 256 * j]);
#pragma unroll
            for (int i = 0; i < 4; ++i) {
                const unsigned u = __float_as_uint(v[i]);
                keys[j * 4 + i] = (u & 0x80000000u) ? ~u : (u | 0x80000000u);
            }
        }

        // bitwise search for the kth-largest key: largest T with count(>=T) >= k
        unsigned pref = 0u;
        for (int b = 31; b >= 0; --b) {
            const unsigned tt = pref | (1u << b);
            int cnt = 0;
#pragma unroll
            for (int j = 0; j < 16; ++j) cnt += (keys[j] >= tt) ? 1 : 0;
#pragma unroll
            for (int off = 32; off >= 1; off >>= 1) cnt += __shfl_xor(cnt, off, 64);
            if (cnt >= kval) pref = tt;
        }

        // mask = importance >= kth (tie-inclusive); coalesced float4 out
        const float* xr = x + srow * DIM;
        float* orow = out + srow * DIM;
#pragma unroll
        for (int j = 0; j < 4; ++j) {
            const f4 xv = *(const f4*)(xr + 4 * l + 256 * j);
            f4 o;
#pragma unroll
            for (int i = 0; i < 4; ++i) o[i] = (keys[j * 4 + i] >= pref) ? xv[i] : 0.0f;
            *(f4*)(orow + 4 * l + 256 * j) = o;
        }
    }
}

// ---------------------------------------------------------------------------
extern "C" void kernel_launch(void* const* d_in, const int* in_sizes, int n_in,
                              void* d_out, int out_size, void* d_ws, size_t ws_size,
                              hipStream_t stream) {
    const float* x  = (const float*)d_in[0];
    const float* w1 = (const float*)d_in[1];
    const float* b1 = (const float*)d_in[2];
    const float* w2 = (const float*)d_in[3];
    const float* b2 = (const float*)d_in[4];
    const float* wg = (const float*)d_in[5];
    const float* bg = (const float*)d_in[6];
    const float* rm = (const float*)d_in[7];
    const float* rv = (const float*)d_in[8];
    float* out = (float*)d_out;

    double* part = (double*)d_ws;                                  // 256*1024 f64 = 2 MB
    int* kptr = (int*)((char*)d_ws + (size_t)256 * DIM * sizeof(double));

    pool_partial<<<256, 256, 0, stream>>>(x, part);
    tiny_net<<<1, 1024, 0, stream>>>(part, w1, b1, w2, b2,
                                     out + (size_t)SEQ * DIM, kptr);
    panel1_kernel<<<SEQ / BM, CBLOCK, 0, stream>>>(x, wg, out);
    panel23_kernel<<<SEQ / BM, CBLOCK, 0, stream>>>(x, wg, bg, rm, rv, kptr, out);
}

// Round 10
// 999.874 us; speedup vs baseline: 1.2145x; 1.0452x over previous
//
#include <hip/hip_runtime.h>
#include <cstdint>
#include <cstddef>

#define SEQ 32768
#define DIM 1024
#define HID 128
#define KMAXV 103   // int(0.1*1024)+1

using f4 = __attribute__((ext_vector_type(4))) float;
using f2 = __attribute__((ext_vector_type(2))) float;

// ---------------------------------------------------------------------------
// Kernel A: per-block partial column sums of x (f64, deterministic order).
// ---------------------------------------------------------------------------
__global__ __launch_bounds__(256) void pool_partial(const float* __restrict__ x,
                                                    double* __restrict__ part) {
    const int b = blockIdx.x;
    const int t = threadIdx.x;
    const int r0 = b * 128;
    double s0 = 0.0, s1 = 0.0, s2 = 0.0, s3 = 0.0;
    for (int r = 0; r < 128; ++r) {
        const float* row = x + (size_t)(r0 + r) * DIM;
        s0 += (double)row[t];
        s1 += (double)row[t + 256];
        s2 += (double)row[t + 512];
        s3 += (double)row[t + 768];
    }
    double* p = part + (size_t)b * DIM;
    p[t] = s0; p[t + 256] = s1; p[t + 512] = s2; p[t + 768] = s3;
}

// ---------------------------------------------------------------------------
// Kernel B: finish pooling, complexity net (exact erf GELU, sigmoid), k.
// ---------------------------------------------------------------------------
__global__ __launch_bounds__(1024) void tiny_net(const double* __restrict__ part,
                                                 const float* __restrict__ w1,
                                                 const float* __restrict__ b1,
                                                 const float* __restrict__ w2,
                                                 const float* __restrict__ b2,
                                                 float* __restrict__ out_scalars,
                                                 int* __restrict__ kout) {
    __shared__ double pooled[DIM];
    __shared__ double hidv[HID];
    const int t = threadIdx.x;

    double s = 0.0;
    for (int b = 0; b < 256; ++b) s += part[(size_t)b * DIM + t];
    pooled[t] = s / (double)SEQ;
    __syncthreads();

    if (t < HID) {
        double h = (double)b1[t];
        for (int d = 0; d < DIM; ++d) h += pooled[d] * (double)w1[d * HID + t];
        h = 0.5 * h * (1.0 + erf(h * 0.70710678118654752440));
        hidv[t] = h;
    }
    __syncthreads();

    if (t == 0) {
        double z = (double)b2[0];
        for (int j = 0; j < HID; ++j) z += hidv[j] * (double)w2[j];
        double c = 1.0 / (1.0 + exp(-z));
        double ar = 0.01 + 0.09 * c;
        int k = (int)(ar * (double)DIM);  // trunc
        if (k < 1) k = 1;
        if (k > KMAXV) k = KMAXV;
        out_scalars[0] = (float)c;
        out_scalars[1] = (float)ar;
        out_scalars[2] = (float)k;
        *kout = k;
    }
}

// ---------------------------------------------------------------------------
// GEMM with numpy/OpenBLAS f32 semantics — NUMERICS FROZEN: per element,
// sequential-k IEEE fma within panels {384,320,320}, panel sums added in
// order ((P1+P2)+P3). v_pk_fma_f32 performs an independent IEEE f32 fma in
// each 32-bit half -> the two column chains (c2, c2+1) keep exactly the
// per-element op order of rounds 2/3/6/8/9.
//
// x is block-uniform -> uniform f2 loads become s_load_dwordx2 (scalar pipe,
// zero LDS, zero x VGPRs); inline asm op_sel broadcasts the SGPR x-word into
// both halves of the packed FMA (no broadcast movs — the R7 failure).
// w per thread: 2 contiguous cols, f2 global loads, unroll-by-2 two-register-
// set pipeline (4 movs/step instead of 32).
// Split kernels (P1 / P2-accum / P3+select) keep the live set ~55 regs so the
// ~64-VGPR allocator clamp (R4/R5/R9 evidence) causes no in-loop spills.
// ---------------------------------------------------------------------------
#define BM 16
#define CBLOCK 512

// one 4-k FMA step for 16 rows: acc[m] += x[m][k] * w[k] (packed 2 cols)
__device__ __forceinline__ void fma_step(const float* __restrict__ xp,
                                         f2 w0, f2 w1, f2 w2, f2 w3,
                                         f2 acc[16]) {
#pragma unroll
    for (int m = 0; m < 16; ++m) {
        const f2 xab = *(const f2*)(xp + m * DIM);      // uniform -> s_load_dwordx2
        const f2 xcd = *(const f2*)(xp + m * DIM + 2);
        asm("v_pk_fma_f32 %0, %1, %2, %0 op_sel:[0,0,0] op_sel_hi:[0,1,1]"
            : "+v"(acc[m]) : "s"(xab), "v"(w0));        // k+0: broadcast x word0
        asm("v_pk_fma_f32 %0, %1, %2, %0 op_sel:[1,0,0] op_sel_hi:[1,1,1]"
            : "+v"(acc[m]) : "s"(xab), "v"(w1));        // k+1: broadcast x word1
        asm("v_pk_fma_f32 %0, %1, %2, %0 op_sel:[0,0,0] op_sel_hi:[0,1,1]"
            : "+v"(acc[m]) : "s"(xcd), "v"(w2));        // k+2
        asm("v_pk_fma_f32 %0, %1, %2, %0 op_sel:[1,0,0] op_sel_hi:[1,1,1]"
            : "+v"(acc[m]) : "s"(xcd), "v"(w3));        // k+3
    }
}

template<int K0, int K1>
__device__ __forceinline__ void panel_acc(const float* __restrict__ x,
                                          const float* __restrict__ wbase,
                                          int row0, f2 acc[16]) {
#pragma unroll
    for (int m = 0; m < 16; ++m) { acc[m][0] = 0.0f; acc[m][1] = 0.0f; }

    const float* xbase = x + (size_t)row0 * DIM;

    f2 a0 = *(const f2*)(wbase + (size_t)(K0 + 0) * DIM);
    f2 a1 = *(const f2*)(wbase + (size_t)(K0 + 1) * DIM);
    f2 a2 = *(const f2*)(wbase + (size_t)(K0 + 2) * DIM);
    f2 a3 = *(const f2*)(wbase + (size_t)(K0 + 3) * DIM);

    for (int kk0 = K0; kk0 < K1; kk0 += 8) {
        const f2 b0 = *(const f2*)(wbase + (size_t)(kk0 + 4) * DIM);
        const f2 b1 = *(const f2*)(wbase + (size_t)(kk0 + 5) * DIM);
        const f2 b2v = *(const f2*)(wbase + (size_t)(kk0 + 6) * DIM);
        const f2 b3 = *(const f2*)(wbase + (size_t)(kk0 + 7) * DIM);

        fma_step(xbase + kk0, a0, a1, a2, a3, acc);     // k = kk0..kk0+3

        const int kn = (kk0 + 8 < K1) ? kk0 + 8 : K0;   // tail: dummy reload
        const f2 c0 = *(const f2*)(wbase + (size_t)(kn + 0) * DIM);
        const f2 c1 = *(const f2*)(wbase + (size_t)(kn + 1) * DIM);
        const f2 c2v = *(const f2*)(wbase + (size_t)(kn + 2) * DIM);
        const f2 c3 = *(const f2*)(wbase + (size_t)(kn + 3) * DIM);

        fma_step(xbase + kk0 + 4, b0, b1, b2v, b3, acc); // k = kk0+4..kk0+7

        a0 = c0; a1 = c1; a2 = c2v; a3 = c3;
    }
}

__global__ __launch_bounds__(CBLOCK) void panel1_kernel(const float* __restrict__ x,
                                                        const float* __restrict__ wg,
                                                        float* __restrict__ out) {
    const int t = threadIdx.x;
    const int c2 = t << 1;
    const int row0 = blockIdx.x * BM;

    f2 pacc[16];
    panel_acc<0, 384>(x, wg + c2, row0, pacc);

#pragma unroll
    for (int m = 0; m < 16; ++m)
        *(f2*)(out + (size_t)(row0 + m) * DIM + c2) = pacc[m];
}

__global__ __launch_bounds__(CBLOCK) void panel2_kernel(const float* __restrict__ x,
                                                        const float* __restrict__ wg,
                                                        float* __restrict__ out) {
    const int t = threadIdx.x;
    const int c2 = t << 1;
    const int row0 = blockIdx.x * BM;

    f2 pacc[16];
    panel_acc<384, 704>(x, wg + c2, row0, pacc);

#pragma unroll
    for (int m = 0; m < 16; ++m) {
        float* op = out + (size_t)(row0 + m) * DIM + c2;
        f2 d = *(const f2*)op;
        d[0] = d[0] + pacc[m][0];       // fl(P1+P2), plain f32 adds
        d[1] = d[1] + pacc[m][1];
        *(f2*)op = d;
    }
}

__global__ __launch_bounds__(CBLOCK) void panel3_kernel(const float* __restrict__ x,
                                                        const float* __restrict__ wg,
                                                        const float* __restrict__ bg,
                                                        const float* __restrict__ rm,
                                                        const float* __restrict__ rv,
                                                        const int* __restrict__ kptr,
                                                        float* __restrict__ out) {
    __shared__ float lbuf[8 * DIM];

    const int t = threadIdx.x;
    const int c2 = t << 1;
    const int row0 = blockIdx.x * BM;

    f2 pacc[16];
    panel_acc<704, 1024>(x, wg + c2, row0, pacc);

    float dot[16][2];
#pragma unroll
    for (int m = 0; m < 16; ++m) {
        const f2 d = *(const f2*)(out + (size_t)(row0 + m) * DIM + c2);
        dot[m][0] = d[0] + pacc[m][0];  // fl((P1+P2)+P3)
        dot[m][1] = d[1] + pacc[m][1];
    }

    // f32 epilogue, op-for-op as numpy
    const f2 vbg = *(const f2*)(bg + c2);
    const f2 vrm = *(const f2*)(rm + c2);
    const f2 vrv = *(const f2*)(rv + c2);
    f2 vden;
    vden[0] = sqrtf(vrv[0]) + 1e-6f;
    vden[1] = sqrtf(vrv[1]) + 1e-6f;

    f2 imp[16];
#pragma unroll
    for (int m = 0; m < 16; ++m) {
        imp[m][0] = (fabsf(dot[m][0] + vbg[0]) - vrm[0]) / vden[0];
        imp[m][1] = (fabsf(dot[m][1] + vbg[1]) - vrm[1]) / vden[1];
    }

    int kval = *kptr;
    if (kval < 1) kval = 1;
    if (kval > DIM) kval = DIM;

    float (*selbuf)[DIM] = (float (*)[DIM])lbuf;

    // two chunks of 8 rows; one wave per row does exact kth-largest selection
    for (int ch = 0; ch < 2; ++ch) {
        __syncthreads();
#pragma unroll
        for (int m = 0; m < 8; ++m)
            *(f2*)(&selbuf[m][c2]) = imp[ch * 8 + m];
        __syncthreads();

        const int w = t >> 6;    // wave id 0..7 -> row within chunk
        const int l = t & 63;    // lane
        const size_t srow = (size_t)(row0 + ch * 8 + w);

        // monotonic u32 keys for descending f32 order
        unsigned keys[16];
#pragma unroll
        for (int j = 0; j < 4; ++j) {
            const f4 v = *(const f4*)(&selbuf[w][4 * l + 256 * j]);
#pragma unroll
            for (int i = 0; i < 4; ++i) {
                const unsigned u = __float_as_uint(v[i]);
                keys[j * 4 + i] = (u & 0x80000000u) ? ~u : (u | 0x80000000u);
            }
        }

        // bitwise search for the kth-largest key: largest T with count(>=T) >= k
        unsigned pref = 0u;
        for (int b = 31; b >= 0; --b) {
            const unsigned tt = pref | (1u << b);
            int cnt = 0;
#pragma unroll
            for (int j = 0; j < 16; ++j) cnt += (keys[j] >= tt) ? 1 : 0;
#pragma unroll
            for (int off = 32; off >= 1; off >>= 1) cnt += __shfl_xor(cnt, off, 64);
            if (cnt >= kval) pref = tt;
        }

        // mask = importance >= kth (tie-inclusive); coalesced float4 out
        const float* xr = x + srow * DIM;
        float* orow = out + srow * DIM;
#pragma unroll
        for (int j = 0; j < 4; ++j) {
            const f4 xv = *(const f4*)(xr + 4 * l + 256 * j);
            f4 o;
#pragma unroll
            for (int i = 0; i < 4; ++i) o[i] = (keys[j * 4 + i] >= pref) ? xv[i] : 0.0f;
            *(f4*)(orow + 4 * l + 256 * j) = o;
        }
    }
}

// ---------------------------------------------------------------------------
extern "C" void kernel_launch(void* const* d_in, const int* in_sizes, int n_in,
                              void* d_out, int out_size, void* d_ws, size_t ws_size,
                              hipStream_t stream) {
    const float* x  = (const float*)d_in[0];
    const float* w1 = (const float*)d_in[1];
    const float* b1 = (const float*)d_in[2];
    const float* w2 = (const float*)d_in[3];
    const float* b2 = (const float*)d_in[4];
    const float* wg = (const float*)d_in[5];
    const float* bg = (const float*)d_in[6];
    const float* rm = (const float*)d_in[7];
    const float* rv = (const float*)d_in[8];
    float* out = (float*)d_out;

    double* part = (double*)d_ws;                                  // 256*1024 f64 = 2 MB
    int* kptr = (int*)((char*)d_ws + (size_t)256 * DIM * sizeof(double));

    pool_partial<<<256, 256, 0, stream>>>(x, part);
    tiny_net<<<1, 1024, 0, stream>>>(part, w1, b1, w2, b2,
                                     out + (size_t)SEQ * DIM, kptr);
    panel1_kernel<<<SEQ / BM, CBLOCK, 0, stream>>>(x, wg, out);
    panel2_kernel<<<SEQ / BM, CBLOCK, 0, stream>>>(x, wg, out);
    panel3_kernel<<<SEQ / BM, CBLOCK, 0, stream>>>(x, wg, bg, rm, rv, kptr, out);
}